// Round 5
// baseline (448.007 us; speedup 1.0000x reference)
//
#include <hip/hip_runtime.h>
#include <stdint.h>

// Problem constants (fixed by reference)
#define NB 2048           // batch N
#define NI 256            // input dim I
#define NJ 256            // out dim J
#define GK 300            // grid size K
#define KPAD 320          // K padded to multiple of 16
#define KK_PER_I (2*KPAD) // cos/sin interleaved: 640 reduction elems per i
#define NKC2 (NI*KK_PER_I/16)  // 10240 chunk-columns of 16 kk (32x32x16 k-step)
#define CH32_PER_I 20     // 32-kk double-chunks per i
#define SPLITK 32
#define II_PER_S (NI / SPLITK)   // 8 i-values per split-k slice
#define BM 128

typedef __bf16 bf16x8 __attribute__((ext_vector_type(8)));
typedef __bf16 bf16x2 __attribute__((ext_vector_type(2)));
typedef float  f32x16 __attribute__((ext_vector_type(16)));

__device__ __forceinline__ void sincos2pi(float ang, float& c, float& s) {
  float r = ang * 0.15915494309189535f;   // 1/(2*pi)
  r = r - floorf(r);
  c = __builtin_amdgcn_cosf(r);
  s = __builtin_amdgcn_sinf(r);
}

__device__ __forceinline__ unsigned int pkbf(float c, float s) {
  bf16x2 p; p.x = (__bf16)c; p.y = (__bf16)s;
  return __builtin_bit_cast(unsigned int, p);
}

__device__ __forceinline__ void rot(float& c, float& s, float cr, float sr) {
  float nc = c * cr - s * sr;
  s = s * cr + c * sr;
  c = nc;
}

// ---------------------------------------------------------------------------
// Pass 1: coeffs fp32 [2][J][I][300] -> bf16 ws in 32x32x16 MFMA B-frag order.
// Frag(kc2, jt) = 1KB: lane slot 16B at lane*16; lane = (n&31) + 32*kblk;
// slot bytes jj*2, kk = kc2*16 + kblk*8 + jj; kk = i*640 + 2k' + d;
// n = jt*32 + (lane&31); uint low bf16 = cos coeff (d=0), high = sin (d=1).
// Thread task (j, g): g = 4-k' group -> 8 kk = exactly one 16B lane slot;
// source float4s 16B-aligned. Wave writes 1KB contiguous per step.
// ---------------------------------------------------------------------------
__global__ __launch_bounds__(256) void convert_b(const float* __restrict__ coeffs,
                                                 uint4* __restrict__ bw4) {
  const int bid = blockIdx.x;
  const int i  = bid >> 3;
  const int jt = bid & 7;                // 8 j-tiles of 32
  const int t  = (int)threadIdx.x;
  const int n2 = t & 31;
  const int gl = t >> 5;                 // 0..7
  const int j  = jt * 32 + n2;

  const float4* r0 = (const float4*)(coeffs + (size_t)(j * NI + i) * GK);
  const float4* r1 = (const float4*)(coeffs + (size_t)((NJ + j) * NI + i) * GK);

  #pragma unroll
  for (int p = 0; p < 10; p++) {
    const int g = p * 8 + gl;            // 0..79 (k' group of 4; >=75 is pad)
    uint4 w = {0u, 0u, 0u, 0u};
    if (g < GK / 4) {                    // 75 real groups
      float4 a = r0[g];
      float4 b = r1[g];
      w.x = pkbf(a.x, b.x);
      w.y = pkbf(a.y, b.y);
      w.z = pkbf(a.z, b.z);
      w.w = pkbf(a.w, b.w);
    }
    const int kc2 = i * 40 + (g >> 1);   // 16-kk chunk column
    bw4[(size_t)(kc2 * 8 + jt) * 64 + n2 + 32 * (g & 1)] = w;
  }
}

// ---------------------------------------------------------------------------
// Pass 2: out[n][j] = bias[j]
// ---------------------------------------------------------------------------
__global__ __launch_bounds__(256) void init_out(const float* __restrict__ bias,
                                                float* __restrict__ out) {
  const int tid = blockIdx.x * 256 + threadIdx.x;     // 131072 float4s
  float4 b = ((const float4*)bias)[tid & 63];
  ((float4*)out)[tid] = b;
}

// ---------------------------------------------------------------------------
// Pass 3: barrier-free GEMM, 32x32x16 bf16 MFMA. No LDS, no __syncthreads.
// Lane generates its own A-fragment (m=lane&31, k=(lane>>5)*8+j) via
// rotation: per 16-kk step, 4 packs + 3 rot-by-1 + 1 rot-by-5.
// B fragments streamed global->VGPR (dwordx4, lane*16B in a 1KB frag) with a
// 32-kk register double buffer. Block 128m x 256n, 4 waves, wave tile
// 64x128 = 2x4 tiles of 32x32 (acc 128 AGPR). Grid: 16 mt x 32 s = 512.
// ---------------------------------------------------------------------------
__global__ __launch_bounds__(256, 2) void fkan_gemm(const float* __restrict__ x,
                                                    const uint4* __restrict__ bw4,
                                                    float* __restrict__ out) {
  const int bid = blockIdx.x;
  const int mt = bid & 15;
  const int s  = bid >> 4;          // split-k slice (i range s*8 .. s*8+7)
  const int m0 = mt * BM;

  const int t    = (int)threadIdx.x;
  const int lane = t & 63;
  const int wave = t >> 6;
  const int wr = wave >> 1;         // m half (64 rows)
  const int wc = wave & 1;          // n half (128 cols)
  const int q2 = lane >> 5;         // k sub-block (0/1)
  const int ln = lane & 31;         // m row (A) / n col (B) within 32-tile

  f32x16 acc[2][4];
  #pragma unroll
  for (int mm = 0; mm < 2; mm++)
    #pragma unroll
    for (int nn = 0; nn < 4; nn++)
      #pragma unroll
      for (int r = 0; r < 16; r++)
        acc[mm][nn][r] = 0.f;

  // B fragment pointer: frag(kc2, jt=wc*4+nn) at uint4 idx (kc2*8+jt)*64+lane
  const uint4* bp = bw4 + (size_t)(wc * 4) * 64 + lane;

  int kc2 = s * (NKC2 / SPLITK);    // s*320, contiguous through the slice
  uint4 bcur[8], bnxt[8];
  #pragma unroll
  for (int q = 0; q < 8; q++)
    bcur[q] = bp[(size_t)(kc2 + (q >> 2)) * 512 + (q & 3) * 64];

  float stc[2], sts[2], c1a[2], s1a[2], c5a[2], s5a[2];

  #pragma unroll 1
  for (int ii = 0; ii < II_PER_S; ii++) {
    const int i = s * II_PER_S + ii;
    // Per-i trig seeds. Lane's A rows: m0 + wr*64 + mm*32 + ln.
    #pragma unroll
    for (int mm = 0; mm < 2; mm++) {
      const float xv = x[(m0 + wr * 64 + mm * 32 + ln) * NI + i];
      sincos2pi(xv, c1a[mm], s1a[mm]);          // rotate-by-1
      sincos2pi(5.f * xv, c5a[mm], s5a[mm]);    // rotate-by-5 (step advance)
      sincos2pi(xv * (float)(q2 * 4 + 1), stc[mm], sts[mm]);  // state
    }

    #pragma unroll 2
    for (int c = 0; c < CH32_PER_I; c++) {
      // Prefetch next 32-kk double-chunk's 8 B-frags (used next iteration)
      const int kc2n = (kc2 + 2 <= NKC2 - 2) ? kc2 + 2 : kc2;
      #pragma unroll
      for (int q = 0; q < 8; q++)
        bnxt[q] = bp[(size_t)(kc2n + (q >> 2)) * 512 + (q & 3) * 64];

      // A fragments: k' = 16c + ks*8 + q2*4 + {0,1,2,3} (angle x*(k'+1))
      bf16x8 af[2][2];
      #pragma unroll
      for (int mm = 0; mm < 2; mm++) {
        float cc = stc[mm], ss = sts[mm];
        uint4 u0, u1;
        u0.x = pkbf(cc, ss);
        rot(cc, ss, c1a[mm], s1a[mm]); u0.y = pkbf(cc, ss);
        rot(cc, ss, c1a[mm], s1a[mm]); u0.z = pkbf(cc, ss);
        rot(cc, ss, c1a[mm], s1a[mm]); u0.w = pkbf(cc, ss);
        rot(cc, ss, c5a[mm], s5a[mm]);
        u1.x = pkbf(cc, ss);
        rot(cc, ss, c1a[mm], s1a[mm]); u1.y = pkbf(cc, ss);
        rot(cc, ss, c1a[mm], s1a[mm]); u1.z = pkbf(cc, ss);
        rot(cc, ss, c1a[mm], s1a[mm]); u1.w = pkbf(cc, ss);
        rot(cc, ss, c5a[mm], s5a[mm]);
        stc[mm] = cc; sts[mm] = ss;
        af[mm][0] = __builtin_bit_cast(bf16x8, u0);
        af[mm][1] = __builtin_bit_cast(bf16x8, u1);
      }

      // 16 MFMAs (2 ksteps x 2 mm x 4 nn) on previously-loaded chunk
      #pragma unroll
      for (int ks = 0; ks < 2; ks++)
        #pragma unroll
        for (int nn = 0; nn < 4; nn++) {
          const bf16x8 bfr = __builtin_bit_cast(bf16x8, bcur[ks * 4 + nn]);
          #pragma unroll
          for (int mm = 0; mm < 2; mm++)
            acc[mm][nn] = __builtin_amdgcn_mfma_f32_32x32x16_bf16(
                af[mm][ks], bfr, acc[mm][nn], 0, 0, 0);
        }

      #pragma unroll
      for (int q = 0; q < 8; q++) bcur[q] = bnxt[q];
      kc2 += 2;
    }
  }

  // ---- Epilogue: atomics. C/D 32x32: col=lane&31, row=(reg&3)+8*(reg>>2)+4*q2
  const int cb = wc * 128 + ln;
  #pragma unroll
  for (int mm = 0; mm < 2; mm++)
    #pragma unroll
    for (int nn = 0; nn < 4; nn++)
      #pragma unroll
      for (int r = 0; r < 16; r++) {
        const int row = m0 + wr * 64 + mm * 32 + (r & 3) + 8 * (r >> 2) + 4 * q2;
        atomicAdd(&out[row * NJ + cb + nn * 32], acc[mm][nn][r]);
      }
}

// ---------------------------------------------------------------------------
extern "C" void kernel_launch(void* const* d_in, const int* in_sizes, int n_in,
                              void* d_out, int out_size, void* d_ws, size_t ws_size,
                              hipStream_t stream) {
  const float* x      = (const float*)d_in[0];   // [2048, 256]
  const float* coeffs = (const float*)d_in[1];   // [2, 256, 256, 300]
  const float* bias   = (const float*)d_in[2];   // [1, 256]
  float* out = (float*)d_out;                    // [2048, 256] fp32
  uint4* bw4 = (uint4*)d_ws;                     // 83.9 MB bf16 B in frag order

  // Pass 1: B conversion (ws re-poisoned every call, so always rebuild)
  convert_b<<<dim3(NI * 8), dim3(256), 0, stream>>>(coeffs, bw4);
  // Pass 2: out = bias
  init_out<<<dim3(NB * NJ / 4 / 256), dim3(256), 0, stream>>>(bias, out);
  // Pass 3: barrier-free GEMM with split-K atomics
  fkan_gemm<<<dim3(16 * SPLITK), dim3(256), 0, stream>>>(x, (const uint4*)bw4, out);
}